// Round 1
// baseline (163.495 us; speedup 1.0000x reference)
//
#include <hip/hip_runtime.h>

// SpatialDistangleLoss: loss = sum_p |y_p| * (box5x5(|y|)_p - |y_p|) / 25 / (H*W*B)
// y shape (8, 320, 96, 96) fp32 -> 2560 planes of 96x96.

#define HH 96
#define WW 96
#define NPLANES 2560          // 8 * 320
#define STRIP_H 16
#define GXN 24                // 24 groups of 4 columns = 96
#define STRIPS (HH / STRIP_H) // 6
#define TPP (GXN * STRIPS)    // 144 threads per plane
#define TOTAL (TPP * NPLANES) // 368640 = 1440 * 256
#define NBLOCKS (TOTAL / 256)
#define SCALE (1.0f / (25.0f * 96.0f * 96.0f * 8.0f))

__global__ __launch_bounds__(256) void sdl_kernel(const float* __restrict__ y,
                                                  float* __restrict__ out) {
    const int t = blockIdx.x * 256 + threadIdx.x;

    const int gx    = t % GXN;
    const int rest  = t / GXN;
    const int strip = rest % STRIPS;
    const int plane = rest / STRIPS;

    const float* base = y + (size_t)plane * (HH * WW);
    const int wbase = gx * 4;
    const int h0 = strip * STRIP_H;
    const bool has_left  = (wbase >= 4);        // cols wbase-4..wbase-1 exist
    const bool has_right = (wbase <= WW - 8);   // cols wbase+4..wbase+7 exist

    float rs[5][4];  // ring: horizontal 5-sums of |y| for rows r-4..r
    float av[3][4];  // ring: center |y| values for rows r-2..r
#pragma unroll
    for (int k = 0; k < 5; ++k)
#pragma unroll
        for (int j = 0; j < 4; ++j) rs[k][j] = 0.0f;
#pragma unroll
    for (int k = 0; k < 3; ++k)
#pragma unroll
        for (int j = 0; j < 4; ++j) av[k][j] = 0.0f;

    float acc = 0.0f;

#pragma unroll
    for (int i = 0; i < STRIP_H + 4; ++i) {
        const int r = h0 - 2 + i;  // row being loaded
        float x[12];               // cols wbase-4 .. wbase+7, |.| applied
        if ((unsigned)r < (unsigned)HH) {
            const float* rowp = base + r * WW + wbase;
            float4 m = *(const float4*)(rowp);
            float4 l = has_left  ? *(const float4*)(rowp - 4) : make_float4(0, 0, 0, 0);
            float4 rr = has_right ? *(const float4*)(rowp + 4) : make_float4(0, 0, 0, 0);
            x[0] = l.x;  x[1] = l.y;  x[2]  = l.z;  x[3]  = l.w;
            x[4] = m.x;  x[5] = m.y;  x[6]  = m.z;  x[7]  = m.w;
            x[8] = rr.x; x[9] = rr.y; x[10] = rr.z; x[11] = rr.w;
#pragma unroll
            for (int k = 0; k < 12; ++k) x[k] = fabsf(x[k]);
        } else {
#pragma unroll
            for (int k = 0; k < 12; ++k) x[k] = 0.0f;
        }

        // horizontal 5-sums; output col wbase+j needs x[j+2 .. j+6]
#pragma unroll
        for (int j = 0; j < 4; ++j) {
            rs[i % 5][j] = x[j + 2] + x[j + 3] + x[j + 4] + x[j + 5] + x[j + 6];
            av[i % 3][j] = x[j + 4];
        }

        if (i >= 4) {
            // output row h = r - 2, center a loaded at iteration i-2
#pragma unroll
            for (int j = 0; j < 4; ++j) {
                float box = rs[0][j] + rs[1][j] + rs[2][j] + rs[3][j] + rs[4][j];
                float a = av[(i - 2) % 3][j];
                acc += a * (box - a);
            }
        }
    }

    // wave reduction (64 lanes)
#pragma unroll
    for (int off = 32; off > 0; off >>= 1) acc += __shfl_down(acc, off, 64);

    __shared__ float smem[4];
    const int lane = threadIdx.x & 63;
    const int wid  = threadIdx.x >> 6;
    if (lane == 0) smem[wid] = acc;
    __syncthreads();
    if (threadIdx.x == 0) {
        float v = smem[0] + smem[1] + smem[2] + smem[3];
        atomicAdd(out, v * SCALE);
    }
}

extern "C" void kernel_launch(void* const* d_in, const int* in_sizes, int n_in,
                              void* d_out, int out_size, void* d_ws, size_t ws_size,
                              hipStream_t stream) {
    const float* y = (const float*)d_in[0];
    float* out = (float*)d_out;
    hipMemsetAsync(out, 0, sizeof(float), stream);
    sdl_kernel<<<NBLOCKS, 256, 0, stream>>>(y, out);
}

// Round 2
// 150.704 us; speedup vs baseline: 1.0849x; 1.0849x over previous
//
#include <hip/hip_runtime.h>

// SpatialDistangleLoss: loss = sum_p |y_p| * (box5x5(|y|)_p - |y_p|) / 25 / (H*W*B)
// y shape (8, 320, 96, 96) fp32 -> 2560 planes of 96x96.
// One block per plane: stage |y| into LDS (coalesced, each byte fetched once),
// then separable 5x5 box from LDS with rolling row sums.

#define HH 96
#define WW 96
#define NPLANES 2560
#define LSTRIDE 100  // floats; %4==0 keeps float4 LDS ops aligned, %32!=0 spreads banks
#define SCALE (1.0f / (25.0f * 96.0f * 96.0f * 8.0f))

__global__ __launch_bounds__(256, 4) void sdl_kernel(const float* __restrict__ y,
                                                     float* __restrict__ out) {
    __shared__ float s[HH * LSTRIDE];  // 38400 B
    __shared__ float red[4];

    const int tid = threadIdx.x;
    const float* base = y + (size_t)blockIdx.x * (HH * WW);

    // ---- stage plane into LDS as |y| ----
    // 96*96 = 9216 floats = 2304 float4 = 9 per thread, fully coalesced & unique.
#pragma unroll
    for (int k = 0; k < 9; ++k) {
        const int idx = tid + 256 * k;  // 0..2303
        const int row = idx / 24;       // 24 float4 per row
        const int c4  = idx % 24;
        float4 v = *(const float4*)(base + row * WW + c4 * 4);
        float* d = &s[row * LSTRIDE + c4 * 4];
        d[0] = fabsf(v.x);
        d[1] = fabsf(v.y);
        d[2] = fabsf(v.z);
        d[3] = fabsf(v.w);
    }
    __syncthreads();

    // ---- compute from LDS ----
    // 192 active threads: 24 col-groups (4 cols) x 8 row-strips (12 rows).
    float acc = 0.0f;
    if (tid < 192) {
        const int gx    = tid % 24;
        const int strip = tid / 24;  // 0..7
        const bool hl = (gx >= 1);
        const bool hr = (gx <= 22);

        float rs[5][4];  // ring: horizontal 5-sums for the last 5 loaded rows
        float av[3][4];  // ring: center values for the last 3 loaded rows
#pragma unroll
        for (int k = 0; k < 5; ++k)
#pragma unroll
            for (int j = 0; j < 4; ++j) rs[k][j] = 0.0f;
#pragma unroll
        for (int k = 0; k < 3; ++k)
#pragma unroll
            for (int j = 0; j < 4; ++j) av[k][j] = 0.0f;

#pragma unroll
        for (int i = 0; i < 16; ++i) {
            const int ri = strip * 12 - 2 + i;  // row being loaded
            float x[12];                        // cols gx*4-4 .. gx*4+7
            if ((unsigned)ri < (unsigned)HH) {
                const float* rowp = &s[ri * LSTRIDE + gx * 4];
                float4 m = *(const float4*)(rowp);
                float4 l = hl ? *(const float4*)(rowp - 4) : make_float4(0, 0, 0, 0);
                float4 r = hr ? *(const float4*)(rowp + 4) : make_float4(0, 0, 0, 0);
                x[0] = l.x; x[1] = l.y; x[2]  = l.z; x[3]  = l.w;
                x[4] = m.x; x[5] = m.y; x[6]  = m.z; x[7]  = m.w;
                x[8] = r.x; x[9] = r.y; x[10] = r.z; x[11] = r.w;
            } else {
#pragma unroll
                for (int k = 0; k < 12; ++k) x[k] = 0.0f;
            }

#pragma unroll
            for (int j = 0; j < 4; ++j) {
                rs[i % 5][j] = x[j + 2] + x[j + 3] + x[j + 4] + x[j + 5] + x[j + 6];
                av[i % 3][j] = x[j + 4];
            }

            if (i >= 4) {
#pragma unroll
                for (int j = 0; j < 4; ++j) {
                    float box = rs[0][j] + rs[1][j] + rs[2][j] + rs[3][j] + rs[4][j];
                    float a = av[(i - 2) % 3][j];
                    acc += a * (box - a);
                }
            }
        }
    }

    // ---- block reduction ----
#pragma unroll
    for (int off = 32; off > 0; off >>= 1) acc += __shfl_down(acc, off, 64);
    const int lane = tid & 63;
    const int wid  = tid >> 6;
    if (lane == 0) red[wid] = acc;
    __syncthreads();
    if (tid == 0) {
        float v = red[0] + red[1] + red[2] + red[3];
        atomicAdd(out, v * SCALE);
    }
}

extern "C" void kernel_launch(void* const* d_in, const int* in_sizes, int n_in,
                              void* d_out, int out_size, void* d_ws, size_t ws_size,
                              hipStream_t stream) {
    const float* y = (const float*)d_in[0];
    float* out = (float*)d_out;
    hipMemsetAsync(out, 0, sizeof(float), stream);
    sdl_kernel<<<NPLANES, 256, 0, stream>>>(y, out);
}

// Round 3
// 134.444 us; speedup vs baseline: 1.2161x; 1.1209x over previous
//
#include <hip/hip_runtime.h>

// SpatialDistangleLoss: loss = sum_p |y_p| * (box5x5(|y|)_p - |y_p|) / 25 / (H*W*B)
// y shape (8, 320, 96, 96) fp32 -> 2560 planes of 96x96.
// Kernel A: one block per plane, stage |y| into LDS, separable 5x5 box,
//           per-block partial -> d_ws[blockIdx] (plain store, NO atomics:
//           2560 same-address atomicAdds serialized at ~50ns each = ~130us in R1/R2).
// Kernel B: single block reduces 2560 partials, writes scaled loss.

#define HH 96
#define WW 96
#define NPLANES 2560
#define LSTRIDE 100  // floats; %4==0 keeps float4 LDS ops aligned, %32!=0 spreads banks
#define SCALE (1.0f / (25.0f * 96.0f * 96.0f * 8.0f))

__global__ __launch_bounds__(256) void sdl_partial(const float* __restrict__ y,
                                                   float* __restrict__ ws) {
    __shared__ float s[HH * LSTRIDE];  // 38400 B
    __shared__ float red[4];

    const int tid = threadIdx.x;
    const float* base = y + (size_t)blockIdx.x * (HH * WW);

    // ---- stage plane into LDS as |y| ----
    // 96*96 = 9216 floats = 2304 float4 = 9 per thread, fully coalesced & unique.
#pragma unroll
    for (int k = 0; k < 9; ++k) {
        const int idx = tid + 256 * k;  // 0..2303
        const int row = idx / 24;       // 24 float4 per row
        const int c4  = idx % 24;
        float4 v = *(const float4*)(base + row * WW + c4 * 4);
        float* d = &s[row * LSTRIDE + c4 * 4];
        d[0] = fabsf(v.x);
        d[1] = fabsf(v.y);
        d[2] = fabsf(v.z);
        d[3] = fabsf(v.w);
    }
    __syncthreads();

    // ---- compute from LDS ----
    // 192 active threads: 24 col-groups (4 cols) x 8 row-strips (12 rows).
    float acc = 0.0f;
    if (tid < 192) {
        const int gx    = tid % 24;
        const int strip = tid / 24;  // 0..7
        const bool hl = (gx >= 1);
        const bool hr = (gx <= 22);

        float rs[5][4];  // ring: horizontal 5-sums for the last 5 loaded rows
        float av[3][4];  // ring: center values for the last 3 loaded rows
#pragma unroll
        for (int k = 0; k < 5; ++k)
#pragma unroll
            for (int j = 0; j < 4; ++j) rs[k][j] = 0.0f;
#pragma unroll
        for (int k = 0; k < 3; ++k)
#pragma unroll
            for (int j = 0; j < 4; ++j) av[k][j] = 0.0f;

#pragma unroll
        for (int i = 0; i < 16; ++i) {
            const int ri = strip * 12 - 2 + i;  // row being loaded
            float x[12];                        // cols gx*4-4 .. gx*4+7
            if ((unsigned)ri < (unsigned)HH) {
                const float* rowp = &s[ri * LSTRIDE + gx * 4];
                float4 m = *(const float4*)(rowp);
                float4 l = hl ? *(const float4*)(rowp - 4) : make_float4(0, 0, 0, 0);
                float4 r = hr ? *(const float4*)(rowp + 4) : make_float4(0, 0, 0, 0);
                x[0] = l.x; x[1] = l.y; x[2]  = l.z; x[3]  = l.w;
                x[4] = m.x; x[5] = m.y; x[6]  = m.z; x[7]  = m.w;
                x[8] = r.x; x[9] = r.y; x[10] = r.z; x[11] = r.w;
            } else {
#pragma unroll
                for (int k = 0; k < 12; ++k) x[k] = 0.0f;
            }

#pragma unroll
            for (int j = 0; j < 4; ++j) {
                rs[i % 5][j] = x[j + 2] + x[j + 3] + x[j + 4] + x[j + 5] + x[j + 6];
                av[i % 3][j] = x[j + 4];
            }

            if (i >= 4) {
#pragma unroll
                for (int j = 0; j < 4; ++j) {
                    float box = rs[0][j] + rs[1][j] + rs[2][j] + rs[3][j] + rs[4][j];
                    float a = av[(i - 2) % 3][j];
                    acc += a * (box - a);
                }
            }
        }
    }

    // ---- block reduction -> plain store of partial ----
#pragma unroll
    for (int off = 32; off > 0; off >>= 1) acc += __shfl_down(acc, off, 64);
    const int lane = tid & 63;
    const int wid  = tid >> 6;
    if (lane == 0) red[wid] = acc;
    __syncthreads();
    if (tid == 0) {
        ws[blockIdx.x] = red[0] + red[1] + red[2] + red[3];
    }
}

__global__ __launch_bounds__(256) void sdl_finish(const float* __restrict__ ws,
                                                  float* __restrict__ out) {
    const int tid = threadIdx.x;
    float acc = 0.0f;
#pragma unroll
    for (int k = 0; k < NPLANES / 256; ++k) acc += ws[tid + 256 * k];
#pragma unroll
    for (int off = 32; off > 0; off >>= 1) acc += __shfl_down(acc, off, 64);
    __shared__ float red[4];
    const int lane = tid & 63;
    const int wid  = tid >> 6;
    if (lane == 0) red[wid] = acc;
    __syncthreads();
    if (tid == 0) {
        out[0] = (red[0] + red[1] + red[2] + red[3]) * SCALE;
    }
}

extern "C" void kernel_launch(void* const* d_in, const int* in_sizes, int n_in,
                              void* d_out, int out_size, void* d_ws, size_t ws_size,
                              hipStream_t stream) {
    const float* y = (const float*)d_in[0];
    float* ws = (float*)d_ws;
    float* out = (float*)d_out;
    sdl_partial<<<NPLANES, 256, 0, stream>>>(y, ws);
    sdl_finish<<<1, 256, 0, stream>>>(ws, out);
}